// Round 1
// baseline (1830.915 us; speedup 1.0000x reference)
//
#include <hip/hip_runtime.h>
#include <hip/hip_cooperative_groups.h>
#include <math.h>

namespace cg = cooperative_groups;

#define MCENT 16
#define KNN   64
#define NBINS 512
#define CAP   7936
#define FPSB  512
#define FPST  256
#define NPT   16

__device__ __forceinline__ float gelu_f(float x){
    return 0.5f * x * (1.0f + erff(x * 0.70710678118654752440f));
}

__global__ void init_kernel(unsigned int* __restrict__ ghist,
                            unsigned int* __restrict__ cnt){
    int t = threadIdx.x;
    for (int i = t; i < MCENT*NBINS; i += blockDim.x) ghist[i] = 0u;
    if (t < MCENT) cnt[t] = 0u;
}

// ---------------- FPS: cooperative, min_d held in registers ----------------
__global__ __launch_bounds__(FPST, 2) void fps_kernel(
    const float* __restrict__ P, int N,
    unsigned long long* __restrict__ partials,
    int* __restrict__ centers_idx,
    float* __restrict__ cxy,
    float* __restrict__ outC)
{
    cg::grid_group grid = cg::this_grid();
    const int T = FPSB * FPST;
    const int t = blockIdx.x * FPST + threadIdx.x;

    float px[NPT], py[NPT], md[NPT];
#pragma unroll
    for (int i = 0; i < NPT; ++i){
        int g = t + i * T;
        if (g < N){ px[i] = P[2*g]; py[i] = P[2*g+1]; md[i] = 3.402823466e+38f; }
        else      { px[i] = 0.f;   py[i] = 0.f;      md[i] = -1.0f; }   // invalid sentinel
    }

    __shared__ unsigned long long red[FPST];
    __shared__ int s_cur;
    int cur = 0;

    for (int k = 0; k < MCENT; ++k){
        if (blockIdx.x == 0 && threadIdx.x == 0){
            centers_idx[k] = cur;
            float cx = P[2*cur], cy = P[2*cur+1];
            cxy[2*k] = cx; cxy[2*k+1] = cy;
            outC[2*k] = cx; outC[2*k+1] = cy;
        }
        if (k == MCENT-1) break;

        float cx = P[2*cur], cy = P[2*cur+1];
        unsigned long long bk = 0ULL;
#pragma unroll
        for (int i = 0; i < NPT; ++i){
            // match np: (dx*dx) + (dy*dy), no fma contraction
            float dx = __fsub_rn(px[i], cx);
            float dy = __fsub_rn(py[i], cy);
            float d  = __fadd_rn(__fmul_rn(dx,dx), __fmul_rn(dy,dy));
            if (md[i] >= 0.0f){
                float nm = fminf(md[i], d);
                md[i] = nm;
                // max over md, tie -> lowest index (np argmax picks first)
                unsigned long long key =
                    ((unsigned long long)__float_as_uint(nm) << 32)
                    | (unsigned long long)(0xFFFFFFFFu - (unsigned)(t + i*T));
                if (key > bk) bk = key;
            }
        }
        red[threadIdx.x] = bk;
        __syncthreads();
        for (int s = FPST/2; s > 0; s >>= 1){
            if (threadIdx.x < s){
                unsigned long long o = red[threadIdx.x + s];
                if (o > red[threadIdx.x]) red[threadIdx.x] = o;
            }
            __syncthreads();
        }
        if (threadIdx.x == 0) partials[(k & 1) * FPSB + blockIdx.x] = red[0];
        __threadfence();
        grid.sync();

        // every block reduces all partials identically -> no second grid sync
        unsigned long long pb = 0ULL;
        for (int i = threadIdx.x; i < FPSB; i += FPST){
            unsigned long long v = partials[(k & 1) * FPSB + i];
            if (v > pb) pb = v;
        }
        red[threadIdx.x] = pb;
        __syncthreads();
        for (int s = FPST/2; s > 0; s >>= 1){
            if (threadIdx.x < s){
                unsigned long long o = red[threadIdx.x + s];
                if (o > red[threadIdx.x]) red[threadIdx.x] = o;
            }
            __syncthreads();
        }
        if (threadIdx.x == 0)
            s_cur = (int)(0xFFFFFFFFu - (unsigned)(red[0] & 0xFFFFFFFFu));
        __syncthreads();
        cur = s_cur;
    }
}

// ---------------- kNN pass 1: per-center exponent histogram ----------------
__global__ __launch_bounds__(256) void hist_kernel(
    const float* __restrict__ P, int N,
    const float* __restrict__ cxy,
    unsigned int* __restrict__ ghist)
{
    __shared__ unsigned int h[MCENT*NBINS];
    __shared__ float scx[MCENT], scy[MCENT], scs2[MCENT];
    for (int i = threadIdx.x; i < MCENT*NBINS; i += blockDim.x) h[i] = 0u;
    if (threadIdx.x < MCENT){
        float a = cxy[2*threadIdx.x], b = cxy[2*threadIdx.x+1];
        scx[threadIdx.x] = a; scy[threadIdx.x] = b;
        scs2[threadIdx.x] = __fadd_rn(__fmul_rn(a,a), __fmul_rn(b,b));
    }
    __syncthreads();
    const int T = gridDim.x * blockDim.x;
    for (int g = blockIdx.x*blockDim.x + threadIdx.x; g < N; g += T){
        float x = P[2*g], y = P[2*g+1];
        float ps2 = __fadd_rn(__fmul_rn(x,x), __fmul_rn(y,y));
#pragma unroll
        for (int m = 0; m < MCENT; ++m){
            // match reference expanded form: ps2 - 2*dot + cs2
            float dot = __fadd_rn(__fmul_rn(scx[m],x), __fmul_rn(scy[m],y));
            float d2  = __fadd_rn(__fsub_rn(ps2, __fmul_rn(2.0f,dot)), scs2[m]);
            unsigned bin = __float_as_uint(fmaxf(d2, 0.0f)) >> 22;   // exp + 1 mantissa bit
            atomicAdd(&h[m*NBINS + bin], 1u);
        }
    }
    __syncthreads();
    for (int i = threadIdx.x; i < MCENT*NBINS; i += blockDim.x){
        unsigned v = h[i];
        if (v) atomicAdd(&ghist[i], v);
    }
}

__global__ void thr_kernel(const unsigned int* __restrict__ ghist,
                           float* __restrict__ thr){
    int m = threadIdx.x;
    if (m < MCENT){
        unsigned cum = 0; int B = NBINS-1;
        for (int b = 0; b < NBINS; ++b){
            cum += ghist[m*NBINS + b];
            if (cum >= KNN){ B = b; break; }
        }
        thr[m] = __uint_as_float((unsigned)(B+1) << 22);  // all bins <= B pass strictly
    }
}

// ---------------- kNN pass 2: collect candidates below threshold ----------------
__global__ __launch_bounds__(256) void collect_kernel(
    const float* __restrict__ P, int N,
    const float* __restrict__ cxy,
    const float* __restrict__ thr,
    unsigned int* __restrict__ cnt,
    float* __restrict__ cd2,
    int* __restrict__ cidx)
{
    __shared__ float scx[MCENT], scy[MCENT], scs2[MCENT], sth[MCENT];
    if (threadIdx.x < MCENT){
        float a = cxy[2*threadIdx.x], b = cxy[2*threadIdx.x+1];
        scx[threadIdx.x]=a; scy[threadIdx.x]=b;
        scs2[threadIdx.x]=__fadd_rn(__fmul_rn(a,a),__fmul_rn(b,b));
        sth[threadIdx.x]=thr[threadIdx.x];
    }
    __syncthreads();
    const int T = gridDim.x*blockDim.x;
    for (int g = blockIdx.x*blockDim.x + threadIdx.x; g < N; g += T){
        float x=P[2*g], y=P[2*g+1];
        float ps2=__fadd_rn(__fmul_rn(x,x),__fmul_rn(y,y));
#pragma unroll
        for (int m=0;m<MCENT;++m){
            float dot=__fadd_rn(__fmul_rn(scx[m],x),__fmul_rn(scy[m],y));
            float d2=__fadd_rn(__fsub_rn(ps2,__fmul_rn(2.0f,dot)),scs2[m]);
            if (fmaxf(d2,0.0f) < sth[m]){
                unsigned p = atomicAdd(&cnt[m], 1u);
                if (p < CAP){ cd2[m*CAP+p]=d2; cidx[m*CAP+p]=g; }
            }
        }
    }
}

// ---------------- exact top-64 per center over candidates ----------------
__global__ __launch_bounds__(256) void select_kernel(
    const unsigned int* __restrict__ cnt,
    const float* __restrict__ cd2,
    const int* __restrict__ cidx,
    int* __restrict__ nbr)
{
    const int m = blockIdx.x;
    __shared__ unsigned long long keys[CAP];
    __shared__ unsigned long long wred[4];
    unsigned c = cnt[m]; if (c > CAP) c = CAP;
    for (int i = threadIdx.x; i < CAP; i += 256){
        unsigned long long kk = ~0ULL;
        if (i < (int)c){
            unsigned u = __float_as_uint(cd2[m*CAP+i]);
            u = (u & 0x80000000u) ? ~u : (u | 0x80000000u);  // float -> sortable uint
            kk = ((unsigned long long)u << 32)
               | (unsigned long long)(unsigned)cidx[m*CAP+i]; // tie -> lower idx
        }
        keys[i] = kk;
    }
    __syncthreads();
    const int lane = threadIdx.x & 63;
    const int wid  = threadIdx.x >> 6;
    for (int r = 0; r < KNN; ++r){
        unsigned long long best = ~0ULL;
        for (int i = threadIdx.x; i < CAP; i += 256){
            unsigned long long v = keys[i];
            if (v < best) best = v;
        }
        for (int off = 32; off > 0; off >>= 1){
            unsigned long long o = __shfl_xor(best, off, 64);
            if (o < best) best = o;
        }
        if (lane == 0) wred[wid] = best;
        __syncthreads();
        if (threadIdx.x == 0){
            unsigned long long b = wred[0];
            if (wred[1] < b) b = wred[1];
            if (wred[2] < b) b = wred[2];
            if (wred[3] < b) b = wred[3];
            wred[0] = b;
        }
        __syncthreads();
        best = wred[0];
        if (threadIdx.x == 0) nbr[m*KNN + r] = (int)(unsigned)(best & 0xFFFFFFFFu);
        for (int i = threadIdx.x; i < CAP; i += 256)
            if (keys[i] == best) keys[i] = ~0ULL;
        __syncthreads();
    }
}

// ---------------- features + MLP + pooling + head, one block per center ----------------
__global__ __launch_bounds__(256) void mlp_kernel(
    const float* __restrict__ P,
    const float* __restrict__ cxy,
    const int* __restrict__ nbr,
    const float* __restrict__ W1, const float* __restrict__ b1,
    const float* __restrict__ W2, const float* __restrict__ b2,
    const float* __restrict__ W3, const float* __restrict__ b3,
    const float* __restrict__ W4, const float* __restrict__ b4,
    float* __restrict__ outF)
{
    const int m = blockIdx.x;
    const int tid = threadIdx.x;
    __shared__ float feat[KNN][32];
    __shared__ float h1[KNN][64];
    __shared__ float sW2[64*128];
    __shared__ float pmax[2][128], psum[2][128];
    __shared__ float z[260];
    __shared__ float part[2][128];
    __shared__ float zz[128];

    for (int i = tid; i < 64*128; i += 256) sW2[i] = W2[i];

    const float cx = cxy[2*m], cy = cxy[2*m+1];
    if (tid < KNN){
        int g = nbr[m*KNN + tid];
        float dx = P[2*g]   - cx;
        float dy = P[2*g+1] - cy;
        float r  = sqrtf(dx*dx + dy*dy);
        float th = atan2f(dy, dx);
        feat[tid][0]=dx; feat[tid][1]=dy; feat[tid][2]=r;
        feat[tid][3]=sinf(th); feat[tid][4]=cosf(th);
        float fx = dx, fy = dy;      // freqs 1,2,4,8,16,32
#pragma unroll
        for (int l = 0; l < 6; ++l){
            feat[tid][5+4*l+0]=sinf(fx);
            feat[tid][5+4*l+1]=sinf(fy);
            feat[tid][5+4*l+2]=cosf(fx);
            feat[tid][5+4*l+3]=cosf(fy);
            fx += fx; fy += fy;
        }
    }
    __syncthreads();

    // h1 = gelu(per_pt @ W1 + b1): 64x64 outputs
    for (int rep = 0; rep < 16; ++rep){
        int o = rep*256 + tid;
        int k = o >> 6, j = o & 63;
        float acc = b1[j];
#pragma unroll
        for (int c = 0; c < 29; ++c) acc += feat[k][c] * W1[c*64 + j];
        h1[k][j] = gelu_f(acc);
    }
    __syncthreads();

    // h2 = gelu(h1 @ W2 + b2) with fused max/mean pooling over k
    {
        int j = tid & 127, kh = tid >> 7;
        float lmax = -3.402823466e+38f, lsum = 0.f;
        for (int kk = 0; kk < 32; ++kk){
            int k = kh*32 + kk;
            float acc = b2[j];
#pragma unroll 8
            for (int i = 0; i < 64; ++i) acc += h1[k][i] * sW2[i*128 + j];
            float v = gelu_f(acc);
            lmax = fmaxf(lmax, v);
            lsum += v;
        }
        pmax[kh][j] = lmax; psum[kh][j] = lsum;
    }
    __syncthreads();
    if (tid < 128){
        z[tid]       = fmaxf(pmax[0][tid], pmax[1][tid]);
        z[128 + tid] = (psum[0][tid] + psum[1][tid]) * (1.0f/64.0f);
    }
    if (tid < 64){   // r stats in wave 0
        float r = feat[tid][2];
        float s = r, mx = r, mn = r;
        for (int off = 1; off < 64; off <<= 1){
            s  += __shfl_xor(s, off, 64);
            mx  = fmaxf(mx, __shfl_xor(mx, off, 64));
            mn  = fminf(mn, __shfl_xor(mn, off, 64));
        }
        float mean = s * (1.0f/64.0f);
        float dv = (r-mean)*(r-mean);
        for (int off = 1; off < 64; off <<= 1) dv += __shfl_xor(dv, off, 64);
        if (tid == 0){
            z[256]=mean; z[257]=mx; z[258]=mn; z[259]=sqrtf(dv*(1.0f/63.0f));
        }
    }
    __syncthreads();

    // head: gelu(z @ W3 + b3) @ W4 + b4
    {
        int j = tid & 127, half = tid >> 7;
        float acc = 0.f;
        for (int i = half*130; i < half*130+130; ++i) acc += z[i]*W3[i*128+j];
        part[half][j] = acc;
    }
    __syncthreads();
    if (tid < 128) zz[tid] = gelu_f(part[0][tid] + part[1][tid] + b3[tid]);
    __syncthreads();
    {
        int j = tid & 127, half = tid >> 7;
        float acc = 0.f;
        for (int i = half*64; i < half*64+64; ++i) acc += zz[i]*W4[i*128+j];
        part[half][j] = acc;
    }
    __syncthreads();
    if (tid < 128) outF[m*128 + tid] = part[0][tid] + part[1][tid] + b4[tid];
}

extern "C" void kernel_launch(void* const* d_in, const int* in_sizes, int n_in,
                              void* d_out, int out_size, void* d_ws, size_t ws_size,
                              hipStream_t stream)
{
    const float* P  = (const float*)d_in[0];
    const float* W1 = (const float*)d_in[1];
    const float* b1 = (const float*)d_in[2];
    const float* W2 = (const float*)d_in[3];
    const float* b2 = (const float*)d_in[4];
    const float* W3 = (const float*)d_in[5];
    const float* b3 = (const float*)d_in[6];
    const float* W4 = (const float*)d_in[7];
    const float* b4 = (const float*)d_in[8];
    int N = in_sizes[0] / 2;
    float* outF = (float*)d_out;               // [16][128]
    float* outC = outF + MCENT*128;            // [16][2]
    (void)n_in; (void)out_size; (void)ws_size;

    char* base = (char*)d_ws;
    size_t off = 0;
    auto take = [&](size_t bytes)->char*{
        char* p = base + off;
        off = (off + bytes + 255) & ~(size_t)255;
        return p;
    };
    unsigned long long* partials = (unsigned long long*)take(2*FPSB*8);
    int*   centers_idx = (int*)  take(MCENT*4);
    float* cxy         = (float*)take(MCENT*2*4);
    unsigned int* ghist= (unsigned int*)take(MCENT*NBINS*4);
    unsigned int* cnt  = (unsigned int*)take(MCENT*4);
    float* thr         = (float*)take(MCENT*4);
    int*   nbr         = (int*)  take(MCENT*KNN*4);
    float* cd2         = (float*)take((size_t)MCENT*CAP*4);
    int*   cidx        = (int*)  take((size_t)MCENT*CAP*4);

    init_kernel<<<1, 1024, 0, stream>>>(ghist, cnt);

    void* fargs[] = { (void*)&P, (void*)&N, (void*)&partials,
                      (void*)&centers_idx, (void*)&cxy, (void*)&outC };
    hipLaunchCooperativeKernel((const void*)fps_kernel, dim3(FPSB), dim3(FPST),
                               fargs, 0, stream);

    hist_kernel<<<512, 256, 0, stream>>>(P, N, cxy, ghist);
    thr_kernel<<<1, 64, 0, stream>>>(ghist, thr);
    collect_kernel<<<512, 256, 0, stream>>>(P, N, cxy, thr, cnt, cd2, cidx);
    select_kernel<<<MCENT, 256, 0, stream>>>(cnt, cd2, cidx, nbr);
    mlp_kernel<<<MCENT, 256, 0, stream>>>(P, cxy, nbr, W1,b1,W2,b2,W3,b3,W4,b4, outF);
}

// Round 4
// 337.422 us; speedup vs baseline: 5.4262x; 5.4262x over previous
//
#include <hip/hip_runtime.h>
#include <math.h>

#define MCENT 16
#define KNN   64
#define NBINS 512
#define CAP   7936
#define FPSB  512
#define FPST  256

__device__ __forceinline__ float gelu_f(float x){
    return 0.5f * x * (1.0f + erff(x * 0.70710678118654752440f));
}

__global__ void init_kernel(unsigned int* __restrict__ ghist,
                            unsigned int* __restrict__ cnt){
    const int T = gridDim.x * blockDim.x;
    int t = blockIdx.x * blockDim.x + threadIdx.x;
    for (int i = t; i < MCENT*NBINS; i += T) ghist[i] = 0u;
    if (t < MCENT) cnt[t] = 0u;
}

// ---------------- FPS step k: no device-side grid sync, 16 graph launches ----------------
// Step k: (a) reduce step k-1's block partials -> center k (redundantly per block;
// kernel boundary is the coherence point), (b) write cxy/outC[k] (block 0),
// (c) if k < MCENT-1: update min_d vs center k, emit this block's argmax partial.
__global__ __launch_bounds__(FPST) void fps_step(
    const float* __restrict__ P, int N,
    float* __restrict__ min_d,                  // [N] in ws, persists across steps
    unsigned long long* __restrict__ partials,  // [MCENT][FPSB]
    int k,
    float* __restrict__ cxy,
    float* __restrict__ outC)
{
    const int lane = threadIdx.x & 63;
    const int wid  = threadIdx.x >> 6;
    __shared__ unsigned long long wred[FPST/64];
    __shared__ int s_cur;

    int cur = 0;
    if (k > 0){
        unsigned long long pb = 0ULL;
        for (int i = threadIdx.x; i < FPSB; i += FPST){
            unsigned long long v = partials[(k-1)*FPSB + i];
            if (v > pb) pb = v;
        }
#pragma unroll
        for (int off = 32; off > 0; off >>= 1){
            unsigned long long o = __shfl_xor(pb, off, 64);
            if (o > pb) pb = o;
        }
        if (lane == 0) wred[wid] = pb;
        __syncthreads();
        if (threadIdx.x == 0){
            unsigned long long b = wred[0];
#pragma unroll
            for (int w = 1; w < FPST/64; ++w) if (wred[w] > b) b = wred[w];
            s_cur = (int)(0xFFFFFFFFu - (unsigned)(b & 0xFFFFFFFFu));
        }
        __syncthreads();
        cur = s_cur;
    }

    if (blockIdx.x == 0 && threadIdx.x == 0){
        float cx = P[2*cur], cy = P[2*cur+1];
        cxy[2*k] = cx; cxy[2*k+1] = cy;
        outC[2*k] = cx; outC[2*k+1] = cy;
    }
    if (k >= MCENT-1) return;

    const float cx = P[2*cur], cy = P[2*cur+1];
    unsigned long long bk = 0ULL;
    const int T = gridDim.x * FPST;
    for (int g = blockIdx.x*FPST + threadIdx.x; g < N; g += T){
        float2 p = ((const float2*)P)[g];
        // match np: (dx*dx) + (dy*dy), no fma contraction; min is exact
        float dx = __fsub_rn(p.x, cx);
        float dy = __fsub_rn(p.y, cy);
        float d  = __fadd_rn(__fmul_rn(dx,dx), __fmul_rn(dy,dy));
        float nm = (k == 0) ? d : fminf(min_d[g], d);
        min_d[g] = nm;
        // max over min_d, tie -> lowest index (np argmax picks first);
        // min_d >= 0 so raw float bits order correctly
        unsigned long long key =
            ((unsigned long long)__float_as_uint(nm) << 32)
            | (unsigned long long)(0xFFFFFFFFu - (unsigned)g);
        if (key > bk) bk = key;
    }
#pragma unroll
    for (int off = 32; off > 0; off >>= 1){
        unsigned long long o = __shfl_xor(bk, off, 64);
        if (o > bk) bk = o;
    }
    if (lane == 0) wred[wid] = bk;
    __syncthreads();
    if (threadIdx.x == 0){
        unsigned long long b = wred[0];
#pragma unroll
        for (int w = 1; w < FPST/64; ++w) if (wred[w] > b) b = wred[w];
        partials[k*FPSB + blockIdx.x] = b;
    }
}

// ---------------- kNN pass 1: per-center exponent histogram ----------------
__global__ __launch_bounds__(256) void hist_kernel(
    const float* __restrict__ P, int N,
    const float* __restrict__ cxy,
    unsigned int* __restrict__ ghist)
{
    __shared__ unsigned int h[MCENT*NBINS];
    __shared__ float scx[MCENT], scy[MCENT], scs2[MCENT];
    for (int i = threadIdx.x; i < MCENT*NBINS; i += blockDim.x) h[i] = 0u;
    if (threadIdx.x < MCENT){
        float a = cxy[2*threadIdx.x], b = cxy[2*threadIdx.x+1];
        scx[threadIdx.x] = a; scy[threadIdx.x] = b;
        scs2[threadIdx.x] = __fadd_rn(__fmul_rn(a,a), __fmul_rn(b,b));
    }
    __syncthreads();
    const int T = gridDim.x * blockDim.x;
    for (int g = blockIdx.x*blockDim.x + threadIdx.x; g < N; g += T){
        float2 p = ((const float2*)P)[g];
        float x = p.x, y = p.y;
        float ps2 = __fadd_rn(__fmul_rn(x,x), __fmul_rn(y,y));
#pragma unroll
        for (int m = 0; m < MCENT; ++m){
            // match reference expanded form: ps2 - 2*dot + cs2
            float dot = __fadd_rn(__fmul_rn(scx[m],x), __fmul_rn(scy[m],y));
            float d2  = __fadd_rn(__fsub_rn(ps2, __fmul_rn(2.0f,dot)), scs2[m]);
            unsigned bin = __float_as_uint(fmaxf(d2, 0.0f)) >> 22;   // exp + 1 mantissa bit
            atomicAdd(&h[m*NBINS + bin], 1u);
        }
    }
    __syncthreads();
    for (int i = threadIdx.x; i < MCENT*NBINS; i += blockDim.x){
        unsigned v = h[i];
        if (v) atomicAdd(&ghist[i], v);
    }
}

__global__ void thr_kernel(const unsigned int* __restrict__ ghist,
                           float* __restrict__ thr){
    int m = threadIdx.x;
    if (m < MCENT){
        unsigned cum = 0; int B = NBINS-1;
        for (int b = 0; b < NBINS; ++b){
            cum += ghist[m*NBINS + b];
            if (cum >= KNN){ B = b; break; }
        }
        thr[m] = __uint_as_float((unsigned)(B+1) << 22);  // all bins <= B pass strictly
    }
}

// ---------------- kNN pass 2: collect candidates below threshold ----------------
__global__ __launch_bounds__(256) void collect_kernel(
    const float* __restrict__ P, int N,
    const float* __restrict__ cxy,
    const float* __restrict__ thr,
    unsigned int* __restrict__ cnt,
    float* __restrict__ cd2,
    int* __restrict__ cidx)
{
    __shared__ float scx[MCENT], scy[MCENT], scs2[MCENT], sth[MCENT];
    if (threadIdx.x < MCENT){
        float a = cxy[2*threadIdx.x], b = cxy[2*threadIdx.x+1];
        scx[threadIdx.x]=a; scy[threadIdx.x]=b;
        scs2[threadIdx.x]=__fadd_rn(__fmul_rn(a,a),__fmul_rn(b,b));
        sth[threadIdx.x]=thr[threadIdx.x];
    }
    __syncthreads();
    const int T = gridDim.x*blockDim.x;
    for (int g = blockIdx.x*blockDim.x + threadIdx.x; g < N; g += T){
        float2 p = ((const float2*)P)[g];
        float x = p.x, y = p.y;
        float ps2=__fadd_rn(__fmul_rn(x,x),__fmul_rn(y,y));
#pragma unroll
        for (int m=0;m<MCENT;++m){
            float dot=__fadd_rn(__fmul_rn(scx[m],x),__fmul_rn(scy[m],y));
            float d2=__fadd_rn(__fsub_rn(ps2,__fmul_rn(2.0f,dot)),scs2[m]);
            if (fmaxf(d2,0.0f) < sth[m]){
                unsigned p2 = atomicAdd(&cnt[m], 1u);
                if (p2 < CAP){ cd2[m*CAP+p2]=d2; cidx[m*CAP+p2]=g; }
            }
        }
    }
}

// ---------------- exact top-64 per center: rank by pairwise comparison ----------------
__global__ __launch_bounds__(256) void select_kernel(
    const unsigned int* __restrict__ cnt,
    const float* __restrict__ cd2,
    const int* __restrict__ cidx,
    int* __restrict__ nbr)
{
    const int m = blockIdx.x;
    __shared__ unsigned long long keys[CAP];
    unsigned c = cnt[m]; if (c > CAP) c = CAP;
    for (int i = threadIdx.x; i < (int)c; i += 256){
        unsigned u = __float_as_uint(cd2[m*CAP+i]);
        u = (u & 0x80000000u) ? ~u : (u | 0x80000000u);  // float -> sortable uint
        keys[i] = ((unsigned long long)u << 32)
                | (unsigned long long)(unsigned)cidx[m*CAP+i]; // tie -> lower idx
    }
    __syncthreads();
    // each candidate's exact rank = #keys smaller; keys unique (idx in low bits)
    for (int i = threadIdx.x; i < (int)c; i += 256){
        unsigned long long ki = keys[i];
        int rank = 0;
        for (int j = 0; j < (int)c; ++j) rank += (keys[j] < ki);
        if (rank < KNN) nbr[m*KNN + rank] = (int)(unsigned)(ki & 0xFFFFFFFFu);
    }
}

// ---------------- features + MLP + pooling + head, one block per center ----------------
__global__ __launch_bounds__(256) void mlp_kernel(
    const float* __restrict__ P,
    const float* __restrict__ cxy,
    const int* __restrict__ nbr,
    const float* __restrict__ W1, const float* __restrict__ b1,
    const float* __restrict__ W2, const float* __restrict__ b2,
    const float* __restrict__ W3, const float* __restrict__ b3,
    const float* __restrict__ W4, const float* __restrict__ b4,
    float* __restrict__ outF)
{
    const int m = blockIdx.x;
    const int tid = threadIdx.x;
    __shared__ float feat[KNN][32];
    __shared__ float h1[KNN][64];
    __shared__ float sW2[64*128];
    __shared__ float pmax[2][128], psum[2][128];
    __shared__ float z[260];
    __shared__ float part[2][128];
    __shared__ float zz[128];

    for (int i = tid; i < 64*128; i += 256) sW2[i] = W2[i];

    const float cx = cxy[2*m], cy = cxy[2*m+1];
    if (tid < KNN){
        int g = nbr[m*KNN + tid];
        float dx = P[2*g]   - cx;
        float dy = P[2*g+1] - cy;
        float r  = sqrtf(dx*dx + dy*dy);
        float th = atan2f(dy, dx);
        feat[tid][0]=dx; feat[tid][1]=dy; feat[tid][2]=r;
        feat[tid][3]=sinf(th); feat[tid][4]=cosf(th);
        float fx = dx, fy = dy;      // freqs 1,2,4,8,16,32
#pragma unroll
        for (int l = 0; l < 6; ++l){
            feat[tid][5+4*l+0]=sinf(fx);
            feat[tid][5+4*l+1]=sinf(fy);
            feat[tid][5+4*l+2]=cosf(fx);
            feat[tid][5+4*l+3]=cosf(fy);
            fx += fx; fy += fy;
        }
    }
    __syncthreads();

    // h1 = gelu(per_pt @ W1 + b1): 64x64 outputs
    for (int rep = 0; rep < 16; ++rep){
        int o = rep*256 + tid;
        int k = o >> 6, j = o & 63;
        float acc = b1[j];
#pragma unroll
        for (int c = 0; c < 29; ++c) acc += feat[k][c] * W1[c*64 + j];
        h1[k][j] = gelu_f(acc);
    }
    __syncthreads();

    // h2 = gelu(h1 @ W2 + b2) with fused max/mean pooling over k
    {
        int j = tid & 127, kh = tid >> 7;
        float lmax = -3.402823466e+38f, lsum = 0.f;
        for (int kk = 0; kk < 32; ++kk){
            int k = kh*32 + kk;
            float acc = b2[j];
#pragma unroll 8
            for (int i = 0; i < 64; ++i) acc += h1[k][i] * sW2[i*128 + j];
            float v = gelu_f(acc);
            lmax = fmaxf(lmax, v);
            lsum += v;
        }
        pmax[kh][j] = lmax; psum[kh][j] = lsum;
    }
    __syncthreads();
    if (tid < 128){
        z[tid]       = fmaxf(pmax[0][tid], pmax[1][tid]);
        z[128 + tid] = (psum[0][tid] + psum[1][tid]) * (1.0f/64.0f);
    }
    if (tid < 64){   // r stats in wave 0
        float r = feat[tid][2];
        float s = r, mx = r, mn = r;
        for (int off = 1; off < 64; off <<= 1){
            s  += __shfl_xor(s, off, 64);
            mx  = fmaxf(mx, __shfl_xor(mx, off, 64));
            mn  = fminf(mn, __shfl_xor(mn, off, 64));
        }
        float mean = s * (1.0f/64.0f);
        float dv = (r-mean)*(r-mean);
        for (int off = 1; off < 64; off <<= 1) dv += __shfl_xor(dv, off, 64);
        if (tid == 0){
            z[256]=mean; z[257]=mx; z[258]=mn; z[259]=sqrtf(dv*(1.0f/63.0f));
        }
    }
    __syncthreads();

    // head: gelu(z @ W3 + b3) @ W4 + b4
    {
        int j = tid & 127, half = tid >> 7;
        float acc = 0.f;
        for (int i = half*130; i < half*130+130; ++i) acc += z[i]*W3[i*128+j];
        part[half][j] = acc;
    }
    __syncthreads();
    if (tid < 128) zz[tid] = gelu_f(part[0][tid] + part[1][tid] + b3[tid]);
    __syncthreads();
    {
        int j = tid & 127, half = tid >> 7;
        float acc = 0.f;
        for (int i = half*64; i < half*64+64; ++i) acc += zz[i]*W4[i*128+j];
        part[half][j] = acc;
    }
    __syncthreads();
    if (tid < 128) outF[m*128 + tid] = part[0][tid] + part[1][tid] + b4[tid];
}

extern "C" void kernel_launch(void* const* d_in, const int* in_sizes, int n_in,
                              void* d_out, int out_size, void* d_ws, size_t ws_size,
                              hipStream_t stream)
{
    const float* P  = (const float*)d_in[0];
    const float* W1 = (const float*)d_in[1];
    const float* b1 = (const float*)d_in[2];
    const float* W2 = (const float*)d_in[3];
    const float* b2 = (const float*)d_in[4];
    const float* W3 = (const float*)d_in[5];
    const float* b3 = (const float*)d_in[6];
    const float* W4 = (const float*)d_in[7];
    const float* b4 = (const float*)d_in[8];
    int N = in_sizes[0] / 2;
    float* outF = (float*)d_out;               // [16][128]
    float* outC = outF + MCENT*128;            // [16][2]
    (void)n_in; (void)out_size; (void)ws_size;

    char* base = (char*)d_ws;
    size_t off = 0;
    auto take = [&](size_t bytes)->char*{
        char* p = base + off;
        off = (off + bytes + 255) & ~(size_t)255;
        return p;
    };
    unsigned long long* partials = (unsigned long long*)take((size_t)MCENT*FPSB*8);
    float* cxy         = (float*)take(MCENT*2*4);
    unsigned int* ghist= (unsigned int*)take(MCENT*NBINS*4);
    unsigned int* cnt  = (unsigned int*)take(MCENT*4);
    float* thr         = (float*)take(MCENT*4);
    int*   nbr         = (int*)  take(MCENT*KNN*4);
    float* cd2         = (float*)take((size_t)MCENT*CAP*4);
    int*   cidx        = (int*)  take((size_t)MCENT*CAP*4);
    float* min_d       = (float*)take((size_t)N*4);

    init_kernel<<<32, 256, 0, stream>>>(ghist, cnt);

    // FPS: 16 plain launches; kernel boundaries are the grid-wide sync
    for (int k = 0; k < MCENT-1; ++k)
        fps_step<<<FPSB, FPST, 0, stream>>>(P, N, min_d, partials, k, cxy, outC);
    fps_step<<<1, FPST, 0, stream>>>(P, N, min_d, partials, MCENT-1, cxy, outC);

    hist_kernel<<<512, 256, 0, stream>>>(P, N, cxy, ghist);
    thr_kernel<<<1, 64, 0, stream>>>(ghist, thr);
    collect_kernel<<<512, 256, 0, stream>>>(P, N, cxy, thr, cnt, cd2, cidx);
    select_kernel<<<MCENT, 256, 0, stream>>>(cnt, cd2, cidx, nbr);
    mlp_kernel<<<MCENT, 256, 0, stream>>>(P, cxy, nbr, W1,b1,W2,b2,W3,b3,W4,b4, outF);
}

// Round 6
// 310.616 us; speedup vs baseline: 5.8945x; 1.0863x over previous
//
#include <hip/hip_runtime.h>
#include <math.h>

#define MCENT 16
#define KNN   64
#define NBINS 512
#define CAP   7936
#define FPSB  512
#define FPST  256
#define MLPT  1024

__device__ __forceinline__ float gelu_f(float x){
    return 0.5f * x * (1.0f + erff(x * 0.70710678118654752440f));
}

// ---------------- FPS step k: no device-side grid sync, 16 graph launches ----------------
// Step k: (a) reduce step k-1's block partials -> center k (redundantly per block;
// kernel boundary is the coherence point), (b) write cxy/outC[k] (block 0),
// (c) if k < MCENT-1: update min_d vs center k (2 pts/thread, float4), emit partial.
// k==0 additionally zero-inits ghist/cnt (replaces init_kernel).
__global__ __launch_bounds__(FPST) void fps_step(
    const float* __restrict__ P, int N,
    float* __restrict__ min_d,                  // [N] in ws, persists across steps
    unsigned long long* __restrict__ partials,  // [MCENT][FPSB]
    int k,
    float* __restrict__ cxy,
    float* __restrict__ outC,
    unsigned int* __restrict__ ghist,
    unsigned int* __restrict__ cnt)
{
    const int lane = threadIdx.x & 63;
    const int wid  = threadIdx.x >> 6;
    __shared__ unsigned long long wred[FPST/64];
    __shared__ int s_cur;

    if (k == 0){
        int gi = blockIdx.x*FPST + threadIdx.x;
        if (gi < MCENT*NBINS) ghist[gi] = 0u;
        if (gi < MCENT) cnt[gi] = 0u;
    }

    int cur = 0;
    if (k > 0){
        unsigned long long pb = 0ULL;
        for (int i = threadIdx.x; i < FPSB; i += FPST){
            unsigned long long v = partials[(k-1)*FPSB + i];
            if (v > pb) pb = v;
        }
#pragma unroll
        for (int off = 32; off > 0; off >>= 1){
            unsigned long long o = __shfl_xor(pb, off, 64);
            if (o > pb) pb = o;
        }
        if (lane == 0) wred[wid] = pb;
        __syncthreads();
        if (threadIdx.x == 0){
            unsigned long long b = wred[0];
#pragma unroll
            for (int w = 1; w < FPST/64; ++w) if (wred[w] > b) b = wred[w];
            s_cur = (int)(0xFFFFFFFFu - (unsigned)(b & 0xFFFFFFFFu));
        }
        __syncthreads();
        cur = s_cur;
    }

    if (blockIdx.x == 0 && threadIdx.x == 0){
        float cx = P[2*cur], cy = P[2*cur+1];
        cxy[2*k] = cx; cxy[2*k+1] = cy;
        outC[2*k] = cx; outC[2*k+1] = cy;
    }
    if (k >= MCENT-1) return;

    const float cx = P[2*cur], cy = P[2*cur+1];
    unsigned long long bk = 0ULL;
    const int T  = gridDim.x * FPST;
    const int NP = N >> 1;
    for (int q = blockIdx.x*FPST + threadIdx.x; q < NP; q += T){
        float4 p = ((const float4*)P)[q];           // (x0,y0,x1,y1)
        // match np: (dx*dx) + (dy*dy), no fma contraction; min is exact
        float dx0 = __fsub_rn(p.x, cx), dy0 = __fsub_rn(p.y, cy);
        float d0  = __fadd_rn(__fmul_rn(dx0,dx0), __fmul_rn(dy0,dy0));
        float dx1 = __fsub_rn(p.z, cx), dy1 = __fsub_rn(p.w, cy);
        float d1  = __fadd_rn(__fmul_rn(dx1,dx1), __fmul_rn(dy1,dy1));
        float2 mp;
        if (k == 0){ mp.x = d0; mp.y = d1; }
        else {
            mp = ((const float2*)min_d)[q];
            mp.x = fminf(mp.x, d0); mp.y = fminf(mp.y, d1);
        }
        ((float2*)min_d)[q] = mp;
        int g = 2*q;
        // max over min_d, tie -> lowest index (np argmax picks first); min_d >= 0
        unsigned long long k0 =
            ((unsigned long long)__float_as_uint(mp.x) << 32)
            | (unsigned long long)(0xFFFFFFFFu - (unsigned)g);
        unsigned long long k1 =
            ((unsigned long long)__float_as_uint(mp.y) << 32)
            | (unsigned long long)(0xFFFFFFFFu - (unsigned)(g+1));
        if (k0 > bk) bk = k0;
        if (k1 > bk) bk = k1;
    }
    if ((N & 1) && blockIdx.x == 0 && threadIdx.x == 0){
        int g = N-1;
        float dx = __fsub_rn(P[2*g], cx), dy = __fsub_rn(P[2*g+1], cy);
        float d  = __fadd_rn(__fmul_rn(dx,dx), __fmul_rn(dy,dy));
        float nm = (k == 0) ? d : fminf(min_d[g], d);
        min_d[g] = nm;
        unsigned long long kk =
            ((unsigned long long)__float_as_uint(nm) << 32)
            | (unsigned long long)(0xFFFFFFFFu - (unsigned)g);
        if (kk > bk) bk = kk;
    }
#pragma unroll
    for (int off = 32; off > 0; off >>= 1){
        unsigned long long o = __shfl_xor(bk, off, 64);
        if (o > bk) bk = o;
    }
    if (lane == 0) wred[wid] = bk;
    __syncthreads();
    if (threadIdx.x == 0){
        unsigned long long b = wred[0];
#pragma unroll
        for (int w = 1; w < FPST/64; ++w) if (wred[w] > b) b = wred[w];
        partials[k*FPSB + blockIdx.x] = b;
    }
}

// ---------------- kNN pass 1: per-center exponent histogram (2 pts/thread) ----------------
__global__ __launch_bounds__(256) void hist_kernel(
    const float* __restrict__ P, int N,
    const float* __restrict__ cxy,
    unsigned int* __restrict__ ghist)
{
    __shared__ unsigned int h[MCENT*NBINS];
    __shared__ float scx[MCENT], scy[MCENT], scs2[MCENT];
    for (int i = threadIdx.x; i < MCENT*NBINS; i += blockDim.x) h[i] = 0u;
    if (threadIdx.x < MCENT){
        float a = cxy[2*threadIdx.x], b = cxy[2*threadIdx.x+1];
        scx[threadIdx.x] = a; scy[threadIdx.x] = b;
        scs2[threadIdx.x] = __fadd_rn(__fmul_rn(a,a), __fmul_rn(b,b));
    }
    __syncthreads();
    const int T  = gridDim.x * blockDim.x;
    const int NP = N >> 1;
    for (int q = blockIdx.x*blockDim.x + threadIdx.x; q < NP; q += T){
        float4 p = ((const float4*)P)[q];
        float ps20 = __fadd_rn(__fmul_rn(p.x,p.x), __fmul_rn(p.y,p.y));
        float ps21 = __fadd_rn(__fmul_rn(p.z,p.z), __fmul_rn(p.w,p.w));
#pragma unroll
        for (int m = 0; m < MCENT; ++m){
            // match reference expanded form: ps2 - 2*dot + cs2
            float dot0 = __fadd_rn(__fmul_rn(scx[m],p.x), __fmul_rn(scy[m],p.y));
            float d20  = __fadd_rn(__fsub_rn(ps20, __fmul_rn(2.0f,dot0)), scs2[m]);
            atomicAdd(&h[m*NBINS + (__float_as_uint(fmaxf(d20,0.0f)) >> 22)], 1u);
            float dot1 = __fadd_rn(__fmul_rn(scx[m],p.z), __fmul_rn(scy[m],p.w));
            float d21  = __fadd_rn(__fsub_rn(ps21, __fmul_rn(2.0f,dot1)), scs2[m]);
            atomicAdd(&h[m*NBINS + (__float_as_uint(fmaxf(d21,0.0f)) >> 22)], 1u);
        }
    }
    if ((N & 1) && blockIdx.x == 0 && threadIdx.x == 0){
        float x = P[2*(N-1)], y = P[2*(N-1)+1];
        float ps2 = __fadd_rn(__fmul_rn(x,x), __fmul_rn(y,y));
        for (int m = 0; m < MCENT; ++m){
            float dot = __fadd_rn(__fmul_rn(scx[m],x), __fmul_rn(scy[m],y));
            float d2  = __fadd_rn(__fsub_rn(ps2, __fmul_rn(2.0f,dot)), scs2[m]);
            atomicAdd(&h[m*NBINS + (__float_as_uint(fmaxf(d2,0.0f)) >> 22)], 1u);
        }
    }
    __syncthreads();
    for (int i = threadIdx.x; i < MCENT*NBINS; i += blockDim.x){
        unsigned v = h[i];
        if (v) atomicAdd(&ghist[i], v);
    }
}

__global__ void thr_kernel(const unsigned int* __restrict__ ghist,
                           float* __restrict__ thr){
    int m = threadIdx.x;
    if (m < MCENT){
        unsigned cum = 0; int B = NBINS-1;
        for (int b = 0; b < NBINS; ++b){
            cum += ghist[m*NBINS + b];
            if (cum >= KNN){ B = b; break; }
        }
        thr[m] = __uint_as_float((unsigned)(B+1) << 22);  // all bins <= B pass strictly
    }
}

// ---------------- kNN pass 2: collect candidates below threshold (2 pts/thread) ----------------
__global__ __launch_bounds__(256) void collect_kernel(
    const float* __restrict__ P, int N,
    const float* __restrict__ cxy,
    const float* __restrict__ thr,
    unsigned int* __restrict__ cnt,
    float* __restrict__ cd2,
    int* __restrict__ cidx)
{
    __shared__ float scx[MCENT], scy[MCENT], scs2[MCENT], sth[MCENT];
    if (threadIdx.x < MCENT){
        float a = cxy[2*threadIdx.x], b = cxy[2*threadIdx.x+1];
        scx[threadIdx.x]=a; scy[threadIdx.x]=b;
        scs2[threadIdx.x]=__fadd_rn(__fmul_rn(a,a),__fmul_rn(b,b));
        sth[threadIdx.x]=thr[threadIdx.x];
    }
    __syncthreads();
    const int T  = gridDim.x*blockDim.x;
    const int NP = N >> 1;
    for (int q = blockIdx.x*blockDim.x + threadIdx.x; q < NP; q += T){
        float4 p = ((const float4*)P)[q];
        float ps20 = __fadd_rn(__fmul_rn(p.x,p.x), __fmul_rn(p.y,p.y));
        float ps21 = __fadd_rn(__fmul_rn(p.z,p.z), __fmul_rn(p.w,p.w));
        int g = 2*q;
#pragma unroll
        for (int m = 0; m < MCENT; ++m){
            float dot0 = __fadd_rn(__fmul_rn(scx[m],p.x), __fmul_rn(scy[m],p.y));
            float d20  = __fadd_rn(__fsub_rn(ps20, __fmul_rn(2.0f,dot0)), scs2[m]);
            if (fmaxf(d20,0.0f) < sth[m]){
                unsigned pos = atomicAdd(&cnt[m], 1u);
                if (pos < CAP){ cd2[m*CAP+pos]=d20; cidx[m*CAP+pos]=g; }
            }
            float dot1 = __fadd_rn(__fmul_rn(scx[m],p.z), __fmul_rn(scy[m],p.w));
            float d21  = __fadd_rn(__fsub_rn(ps21, __fmul_rn(2.0f,dot1)), scs2[m]);
            if (fmaxf(d21,0.0f) < sth[m]){
                unsigned pos = atomicAdd(&cnt[m], 1u);
                if (pos < CAP){ cd2[m*CAP+pos]=d21; cidx[m*CAP+pos]=g+1; }
            }
        }
    }
    if ((N & 1) && blockIdx.x == 0 && threadIdx.x == 0){
        int g = N-1;
        float x = P[2*g], y = P[2*g+1];
        float ps2 = __fadd_rn(__fmul_rn(x,x), __fmul_rn(y,y));
        for (int m = 0; m < MCENT; ++m){
            float dot = __fadd_rn(__fmul_rn(scx[m],x), __fmul_rn(scy[m],y));
            float d2  = __fadd_rn(__fsub_rn(ps2, __fmul_rn(2.0f,dot)), scs2[m]);
            if (fmaxf(d2,0.0f) < sth[m]){
                unsigned pos = atomicAdd(&cnt[m], 1u);
                if (pos < CAP){ cd2[m*CAP+pos]=d2; cidx[m*CAP+pos]=g; }
            }
        }
    }
}

// ---------------- exact top-64 per center: rank by pairwise comparison ----------------
__global__ __launch_bounds__(256) void select_kernel(
    const unsigned int* __restrict__ cnt,
    const float* __restrict__ cd2,
    const int* __restrict__ cidx,
    int* __restrict__ nbr)
{
    const int m = blockIdx.x;
    __shared__ unsigned long long keys[CAP];
    unsigned c = cnt[m]; if (c > CAP) c = CAP;
    for (int i = threadIdx.x; i < (int)c; i += 256){
        unsigned u = __float_as_uint(cd2[m*CAP+i]);
        u = (u & 0x80000000u) ? ~u : (u | 0x80000000u);  // float -> sortable uint
        keys[i] = ((unsigned long long)u << 32)
                | (unsigned long long)(unsigned)cidx[m*CAP+i]; // tie -> lower idx
    }
    __syncthreads();
    // each candidate's exact rank = #keys smaller; keys unique (idx in low bits)
    for (int i = threadIdx.x; i < (int)c; i += 256){
        unsigned long long ki = keys[i];
        int rank = 0;
        for (int j = 0; j < (int)c; ++j) rank += (keys[j] < ki);
        if (rank < KNN) nbr[m*KNN + rank] = (int)(unsigned)(ki & 0xFFFFFFFFu);
    }
}

// ---------------- features + MLP + pooling + head: 1024 threads/center ----------------
__global__ __launch_bounds__(MLPT) void mlp_kernel(
    const float* __restrict__ P,
    const float* __restrict__ cxy,
    const int* __restrict__ nbr,
    const float* __restrict__ W1, const float* __restrict__ b1,
    const float* __restrict__ W2, const float* __restrict__ b2,
    const float* __restrict__ W3, const float* __restrict__ b3,
    const float* __restrict__ W4, const float* __restrict__ b4,
    float* __restrict__ outF)
{
    const int m = blockIdx.x;
    const int tid = threadIdx.x;
    __shared__ float feat[KNN][32];          // 8 KB (29 padded to 32)
    __shared__ float h1s[KNN][64];           // 16 KB
    __shared__ float sW1[29*64];             // 7.4 KB
    __shared__ float sW2[64*128];            // 32 KB
    __shared__ float pmax[8][128], psum[8][128]; // 8 KB
    __shared__ float z[260];
    __shared__ float part[8][128];           // 4 KB
    __shared__ float zz[128];

    // stage W2 (8192 f) and W1 (1856 f) with float4, all issued up front
    {
        const float4* s2 = (const float4*)W2;
        float4* d2 = (float4*)sW2;
        d2[tid]        = s2[tid];
        d2[tid + 1024] = s2[tid + 1024];
        if (tid < 464) ((float4*)sW1)[tid] = ((const float4*)W1)[tid];
    }

    const float cx = cxy[2*m], cy = cxy[2*m+1];
    if (tid < KNN){
        int g = nbr[m*KNN + tid];
        float dx = P[2*g]   - cx;
        float dy = P[2*g+1] - cy;
        float r  = sqrtf(dx*dx + dy*dy);
        float th = atan2f(dy, dx);
        feat[tid][0]=dx; feat[tid][1]=dy; feat[tid][2]=r;
        feat[tid][3]=sinf(th); feat[tid][4]=cosf(th);
        float fx = dx, fy = dy;      // freqs 1,2,4,8,16,32
#pragma unroll
        for (int l = 0; l < 6; ++l){
            feat[tid][5+4*l+0]=sinf(fx);
            feat[tid][5+4*l+1]=sinf(fy);
            feat[tid][5+4*l+2]=cosf(fx);
            feat[tid][5+4*l+3]=cosf(fy);
            fx += fx; fy += fy;
        }
    }
    __syncthreads();

    // h1 = gelu(per_pt @ W1 + b1): 64x64 outputs, 4 per thread
#pragma unroll
    for (int rep = 0; rep < 4; ++rep){
        int o = rep*MLPT + tid;
        int k = o >> 6, j = o & 63;
        float acc = b1[j];
#pragma unroll
        for (int c = 0; c < 29; ++c) acc += feat[k][c] * sW1[c*64 + j];
        h1s[k][j] = gelu_f(acc);
    }
    __syncthreads();

    // h2 = gelu(h1 @ W2 + b2) with fused max/mean pooling: 8 k's per thread
    {
        int j = tid & 127, kh = tid >> 7;
        float lmax = -3.402823466e+38f, lsum = 0.f;
        for (int kk = 0; kk < 8; ++kk){
            int k = kh*8 + kk;
            float acc = b2[j];
#pragma unroll 8
            for (int i = 0; i < 64; ++i) acc += h1s[k][i] * sW2[i*128 + j];
            float v = gelu_f(acc);
            lmax = fmaxf(lmax, v);
            lsum += v;
        }
        pmax[kh][j] = lmax; psum[kh][j] = lsum;
    }
    __syncthreads();
    if (tid < 128){
        float mx = pmax[0][tid], sm = psum[0][tid];
#pragma unroll
        for (int w = 1; w < 8; ++w){ mx = fmaxf(mx, pmax[w][tid]); sm += psum[w][tid]; }
        z[tid]       = mx;
        z[128 + tid] = sm * (1.0f/64.0f);
    }
    if (tid >= 128 && tid < 192){   // r stats on wave 2
        int l = tid - 128;
        float r = feat[l][2];
        float s = r, mx = r, mn = r;
        for (int off = 1; off < 64; off <<= 1){
            s  += __shfl_xor(s, off, 64);
            mx  = fmaxf(mx, __shfl_xor(mx, off, 64));
            mn  = fminf(mn, __shfl_xor(mn, off, 64));
        }
        float mean = s * (1.0f/64.0f);
        float dv = (r-mean)*(r-mean);
        for (int off = 1; off < 64; off <<= 1) dv += __shfl_xor(dv, off, 64);
        if (l == 0){
            z[256]=mean; z[257]=mx; z[258]=mn; z[259]=sqrtf(dv*(1.0f/63.0f));
        }
    }
    __syncthreads();

    // head: gelu(z @ W3 + b3) @ W4 + b4, reduction split 8 ways
    {
        int j = tid & 127, seg = tid >> 7;
        int i0  = (seg < 4) ? seg*33 : 132 + (seg-4)*32;
        int cnt = (seg < 4) ? 33 : 32;
        float acc = 0.f;
        for (int i = i0; i < i0 + cnt; ++i) acc += z[i]*W3[i*128+j];
        part[seg][j] = acc;
    }
    __syncthreads();
    if (tid < 128){
        float a = part[0][tid];
#pragma unroll
        for (int w = 1; w < 8; ++w) a += part[w][tid];
        zz[tid] = gelu_f(a + b3[tid]);
    }
    __syncthreads();
    {
        int j = tid & 127, seg = tid >> 7;
        float acc = 0.f;
#pragma unroll
        for (int i = seg*16; i < seg*16+16; ++i) acc += zz[i]*W4[i*128+j];
        part[seg][j] = acc;
    }
    __syncthreads();
    if (tid < 128){
        float a = part[0][tid];
#pragma unroll
        for (int w = 1; w < 8; ++w) a += part[w][tid];
        outF[m*128 + tid] = a + b4[tid];
    }
}

extern "C" void kernel_launch(void* const* d_in, const int* in_sizes, int n_in,
                              void* d_out, int out_size, void* d_ws, size_t ws_size,
                              hipStream_t stream)
{
    const float* P  = (const float*)d_in[0];
    const float* W1 = (const float*)d_in[1];
    const float* b1 = (const float*)d_in[2];
    const float* W2 = (const float*)d_in[3];
    const float* b2 = (const float*)d_in[4];
    const float* W3 = (const float*)d_in[5];
    const float* b3 = (const float*)d_in[6];
    const float* W4 = (const float*)d_in[7];
    const float* b4 = (const float*)d_in[8];
    int N = in_sizes[0] / 2;
    float* outF = (float*)d_out;               // [16][128]
    float* outC = outF + MCENT*128;            // [16][2]
    (void)n_in; (void)out_size; (void)ws_size;

    char* base = (char*)d_ws;
    size_t off = 0;
    auto take = [&](size_t bytes)->char*{
        char* p = base + off;
        off = (off + bytes + 255) & ~(size_t)255;
        return p;
    };
    unsigned long long* partials = (unsigned long long*)take((size_t)MCENT*FPSB*8);
    float* cxy         = (float*)take(MCENT*2*4);
    unsigned int* ghist= (unsigned int*)take(MCENT*NBINS*4);
    unsigned int* cnt  = (unsigned int*)take(MCENT*4);
    float* thr         = (float*)take(MCENT*4);
    int*   nbr         = (int*)  take(MCENT*KNN*4);
    float* cd2         = (float*)take((size_t)MCENT*CAP*4);
    int*   cidx        = (int*)  take((size_t)MCENT*CAP*4);
    float* min_d       = (float*)take((size_t)N*4);

    // FPS: 16 plain launches; kernel boundaries are the grid-wide sync.
    // k=0 also zero-inits ghist/cnt.
    for (int k = 0; k < MCENT-1; ++k)
        fps_step<<<FPSB, FPST, 0, stream>>>(P, N, min_d, partials, k, cxy, outC,
                                            ghist, cnt);
    fps_step<<<1, FPST, 0, stream>>>(P, N, min_d, partials, MCENT-1, cxy, outC,
                                     ghist, cnt);

    hist_kernel<<<512, 256, 0, stream>>>(P, N, cxy, ghist);
    thr_kernel<<<1, 64, 0, stream>>>(ghist, thr);
    collect_kernel<<<512, 256, 0, stream>>>(P, N, cxy, thr, cnt, cd2, cidx);
    select_kernel<<<MCENT, 256, 0, stream>>>(cnt, cd2, cidx, nbr);
    mlp_kernel<<<MCENT, MLPT, 0, stream>>>(P, cxy, nbr, W1,b1,W2,b2,W3,b3,W4,b4, outF);
}